// Round 6
// baseline (152.790 us; speedup 1.0000x reference)
//
#include <hip/hip_runtime.h>
#include <cmath>

#define BLOCK 256

__device__ __forceinline__ float rlane_f(float v, int k) {
    return __builtin_bit_cast(float, __builtin_amdgcn_readlane(__builtin_bit_cast(int, v), k));
}

// acc layout: per batch b, 4 floats [pos_count, stc_sum, str_sum, pad];
// acc[4*B] (as int) is the block-completion counter. Zeroed by memsetAsync.
// __launch_bounds__(256, 8): pin allocator to <=64 VGPR so 8 waves/SIMD fit —
// rounds 4/5 showed unroll-induced VGPR bloat (136/132) collapses occupancy.
__global__ void __launch_bounds__(BLOCK, 8) ainno_main(
    const float* __restrict__ ss,       // (B, A, 6)
    const float* __restrict__ anchors,  // (A, 4) xywh
    const float* __restrict__ gt,       // (B, K, 4) xywh
    float* __restrict__ acc,
    float* __restrict__ out,
    int A, int K, int B)
{
    __shared__ float red[(BLOCK / 64) * 3];
    const int b    = blockIdx.y;
    const int tid  = threadIdx.x;
    const int lane = tid & 63;
    const int a    = blockIdx.x * BLOCK + tid;
    const int ac   = a < A ? a : A - 1;          // clamp; contribution guarded

    // Prefetch logit before the k-loop: HBM latency hides under ~1400 VALU ops.
    const float* sp = ss + ((size_t)b * A + ac) * 6;
    float logit = sp[4];

    // Lane k of every wave holds GT box k (K == 64 == wave size).
    // Same arithmetic as reference: x2 = x + w, area = (x2-x)*(y2-y).
    float gx1 = 0.f, gy1 = 0.f, gx2 = 0.f, gy2 = 0.f, garr = 0.f;
    if (lane < K) {
        float4 g = ((const float4*)(gt + (size_t)b * K * 4))[lane];
        gx1 = g.x; gy1 = g.y; gx2 = g.x + g.z; gy2 = g.y + g.w;
        garr = (gx2 - gx1) * (gy2 - gy1);
    }

    float4 an = ((const float4*)anchors)[ac];
    float ax  = an.x,        ay  = an.y;
    float axx = an.x + an.z, ayy = an.y + an.w;
    float aar = (axx - ax) * (ayy - ay);

    // Hot loop: pure VALU. 5 readlanes broadcast box k (uniform index ->
    // SGPR broadcast, no memory, no lgkmcnt). Cross-multiplied argmax:
    // one divide total, after the loop, with the exact operands the
    // reference divides -> bit-identical winning IoU. Strict > keeps the
    // first max (matches jnp.argmax).
    float bi = -1.f, bd = 1.f;
    int bk = 0;
    #pragma unroll 4
    for (int k = 0; k < 64; ++k) {
        float sx1 = rlane_f(gx1, k);
        float sy1 = rlane_f(gy1, k);
        float sx2 = rlane_f(gx2, k);
        float sy2 = rlane_f(gy2, k);
        float sar = rlane_f(garr, k);
        float w = fminf(axx, sx2) - fmaxf(ax, sx1);
        float h = fminf(ayy, sy2) - fmaxf(ay, sy1);
        w = fmaxf(w, 0.f); h = fmaxf(h, 0.f);
        float inter = w * h;
        float den = (aar + sar) - inter;
        bool better = inter * bd > bi * den;
        bi = better ? inter : bi;
        bd = better ? den   : bd;
        bk = better ? k     : bk;
    }

    // Winner-box gather via wave shuffle (divergent index -> ds_bpermute).
    // Hoisted out of the divergent branch: inactive-lane reads are undefined.
    float bx1 = __shfl(gx1,  bk, 64);
    float by1 = __shfl(gy1,  bk, 64);
    float bx2 = __shfl(gx2,  bk, 64);
    float by2 = __shfl(gy2,  bk, 64);
    float bar = __shfl(garr, bk, 64);

    float posf = 0.f, stcs = 0.f, strs = 0.f;
    {
        float score = bi / bd;                   // == ref max IoU (same operands)
        bool inb = a < A;
        bool pos = inb && (score >= 0.5f);
        bool neg = inb && (score < 0.4f);
        if (pos | neg) {
            float x = logit;
            float e = expf(-x);
            float p = 1.f / (1.f + e);
            if (pos) {
                posf = 1.f;
                float ce  = log1pf(e);           // softplus(-x) = -log_sigmoid(x)
                float omp = 1.f - p;
                stcs = 0.25f * ce * omp * omp;

                float2 p01 = *(const float2*)(sp);
                float2 p23 = *(const float2*)(sp + 2);
                float px  = p01.x, py = p01.y;
                float pxx = px + p23.x, pyy = py + p23.y;
                float ew = fminf(pxx, bx2) - fmaxf(px, bx1);
                float eh = fminf(pyy, by2) - fmaxf(py, by1);
                ew = fmaxf(ew, 0.f); eh = fmaxf(eh, 0.f);
                float einter = ew * eh;
                float pa = (pxx - px) * (pyy - py);
                float eiou = einter / (pa + bar - einter);
                strs = -logf(eiou + 0.01f);
            } else {
                float ce = log1pf(expf(x));      // softplus(x) = -log_sigmoid(-x)
                stcs = 0.75f * ce * p * p;
            }
        }
    }

    // wave64 shuffle reduction -> LDS across waves -> 3 atomics per block
    float v0 = posf, v1 = stcs, v2 = strs;
    for (int off = 32; off > 0; off >>= 1) {
        v0 += __shfl_down(v0, off, 64);
        v1 += __shfl_down(v1, off, 64);
        v2 += __shfl_down(v2, off, 64);
    }
    const int wave = tid >> 6;
    if (lane == 0) {
        red[wave * 3 + 0] = v0;
        red[wave * 3 + 1] = v1;
        red[wave * 3 + 2] = v2;
    }
    __syncthreads();
    if (tid == 0) {
        float s0 = 0.f, s1 = 0.f, s2 = 0.f;
        for (int w = 0; w < BLOCK / 64; ++w) {
            s0 += red[w * 3 + 0];
            s1 += red[w * 3 + 1];
            s2 += red[w * 3 + 2];
        }
        atomicAdd(&acc[b * 4 + 0], s0);
        atomicAdd(&acc[b * 4 + 1], s1);
        atomicAdd(&acc[b * 4 + 2], s2);
        __threadfence();
        int total = gridDim.x * gridDim.y;
        int old = atomicAdd((int*)(acc + 4 * B), 1);
        if (old == total - 1) {
            // last block finalizes; device-scope atomic reads avoid stale
            // per-XCD L2 lines
            float tot = 0.f;
            for (int bb = 0; bb < B; ++bb) {
                float pc = atomicAdd(&acc[bb * 4 + 0], 0.f);
                float st = atomicAdd(&acc[bb * 4 + 1], 0.f);
                float sr = atomicAdd(&acc[bb * 4 + 2], 0.f);
                float safe = pc > 0.f ? pc : 1.f;
                tot += st / safe;
                if (pc > 0.f) tot += sr / safe;
            }
            out[0] = tot / (float)B;
        }
    }
}

extern "C" void kernel_launch(void* const* d_in, const int* in_sizes, int n_in,
                              void* d_out, int out_size, void* d_ws, size_t ws_size,
                              hipStream_t stream) {
    const float* ss      = (const float*)d_in[0];
    const float* anchors = (const float*)d_in[1];
    const float* gt      = (const float*)d_in[2];
    float* out = (float*)d_out;
    float* acc = (float*)d_ws;
    const int A = in_sizes[1] / 4;
    const int B = in_sizes[0] / (A * 6);
    const int K = in_sizes[2] / (B * 4);

    hipMemsetAsync(acc, 0, ((size_t)B * 4 + 1) * sizeof(float), stream);

    dim3 grid((A + BLOCK - 1) / BLOCK, B);
    ainno_main<<<grid, BLOCK, 0, stream>>>(ss, anchors, gt, acc, out, A, K, B);
}